// Round 1
// baseline (386.242 us; speedup 1.0000x reference)
//
#include <hip/hip_runtime.h>

// ChannelLatentMixer: out[b, 0:64, :] = z[b]; out[b, 64:128, :] = mean over rows
// with same channel id. B=4096, C=32, N=64, D=128.
#define NB      4096
#define NCH     32
#define ND      8192    // 64*128 floats per z row-block
#define OUTROW  16384   // 2*ND floats per output row-block
#define NSPLIT  8       // row-loop split factor per (channel, chunk)
#define NCHUNK  8       // 8 chunks x 1024 floats = 8192-float row

// ---- kernel 1: build per-channel row lists ---------------------------------
__global__ void build_lists_kernel(const int* __restrict__ ch,
                                   int* __restrict__ counts,
                                   int* __restrict__ lists) {
    int b = blockIdx.x * blockDim.x + threadIdx.x;
    if (b < NB) {
        int c = ch[b];
        int pos = atomicAdd(&counts[c], 1);
        lists[c * NB + pos] = b;
    }
}

// ---- kernel 2: copy z->out (z half) + partial channel sums -----------------
// grid = NCH * NCHUNK * NSPLIT blocks of 256 threads.
// block (c, chunk, s) owns column slice [chunk*1024, chunk*1024+1024) and rows
// i = s, s+NSPLIT, ... of channel c's list. Partial sums committed via atomics.
__global__ __launch_bounds__(256) void copy_reduce_kernel(
        const float* __restrict__ z,
        const int* __restrict__ counts,
        const int* __restrict__ lists,
        float* __restrict__ out,
        float* __restrict__ sums) {
    const int bid   = blockIdx.x;
    const int s     = bid & (NSPLIT - 1);
    const int chunk = (bid / NSPLIT) & (NCHUNK - 1);
    const int c     = bid / (NSPLIT * NCHUNK);
    const int off   = chunk * 1024 + threadIdx.x * 4;  // float offset in row
    const int cnt   = counts[c];
    const int* __restrict__ lst = lists + c * NB;

    float4 acc = make_float4(0.f, 0.f, 0.f, 0.f);

    int i = s;
    for (; i + 3 * NSPLIT < cnt; i += 4 * NSPLIT) {
        const int b0 = lst[i];
        const int b1 = lst[i +     NSPLIT];
        const int b2 = lst[i + 2 * NSPLIT];
        const int b3 = lst[i + 3 * NSPLIT];
        const float4 v0 = *(const float4*)(z + (long)b0 * ND + off);
        const float4 v1 = *(const float4*)(z + (long)b1 * ND + off);
        const float4 v2 = *(const float4*)(z + (long)b2 * ND + off);
        const float4 v3 = *(const float4*)(z + (long)b3 * ND + off);
        *(float4*)(out + (long)b0 * OUTROW + off) = v0;
        *(float4*)(out + (long)b1 * OUTROW + off) = v1;
        *(float4*)(out + (long)b2 * OUTROW + off) = v2;
        *(float4*)(out + (long)b3 * OUTROW + off) = v3;
        acc.x += (v0.x + v1.x) + (v2.x + v3.x);
        acc.y += (v0.y + v1.y) + (v2.y + v3.y);
        acc.z += (v0.z + v1.z) + (v2.z + v3.z);
        acc.w += (v0.w + v1.w) + (v2.w + v3.w);
    }
    for (; i < cnt; i += NSPLIT) {
        const int b = lst[i];
        const float4 v = *(const float4*)(z + (long)b * ND + off);
        *(float4*)(out + (long)b * OUTROW + off) = v;
        acc.x += v.x; acc.y += v.y; acc.z += v.z; acc.w += v.w;
    }

    float* dst = sums + (long)c * ND + off;
    atomicAdd(dst + 0, acc.x);
    atomicAdd(dst + 1, acc.y);
    atomicAdd(dst + 2, acc.z);
    atomicAdd(dst + 3, acc.w);
}

// ---- kernel 3: finalize mean + broadcast to aggr half ----------------------
// Same (c, chunk, s) geometry as kernel 2. sums reads are L2-hot (1 MB total).
__global__ __launch_bounds__(256) void broadcast_kernel(
        const int* __restrict__ counts,
        const int* __restrict__ lists,
        const float* __restrict__ sums,
        float* __restrict__ out) {
    const int bid   = blockIdx.x;
    const int s     = bid & (NSPLIT - 1);
    const int chunk = (bid / NSPLIT) & (NCHUNK - 1);
    const int c     = bid / (NSPLIT * NCHUNK);
    const int off   = chunk * 1024 + threadIdx.x * 4;
    const int cnt   = counts[c];
    const int* __restrict__ lst = lists + c * NB;

    const float inv = 1.0f / fmaxf((float)cnt, 1.0f);
    float4 m = *(const float4*)(sums + (long)c * ND + off);
    m.x *= inv; m.y *= inv; m.z *= inv; m.w *= inv;

    int i = s;
    for (; i + 3 * NSPLIT < cnt; i += 4 * NSPLIT) {
        const int b0 = lst[i];
        const int b1 = lst[i +     NSPLIT];
        const int b2 = lst[i + 2 * NSPLIT];
        const int b3 = lst[i + 3 * NSPLIT];
        *(float4*)(out + (long)b0 * OUTROW + ND + off) = m;
        *(float4*)(out + (long)b1 * OUTROW + ND + off) = m;
        *(float4*)(out + (long)b2 * OUTROW + ND + off) = m;
        *(float4*)(out + (long)b3 * OUTROW + ND + off) = m;
    }
    for (; i < cnt; i += NSPLIT) {
        const int b = lst[i];
        *(float4*)(out + (long)b * OUTROW + ND + off) = m;
    }
}

extern "C" void kernel_launch(void* const* d_in, const int* in_sizes, int n_in,
                              void* d_out, int out_size, void* d_ws, size_t ws_size,
                              hipStream_t stream) {
    const float* z  = (const float*)d_in[0];
    const int*   ch = (const int*)d_in[1];
    float*       out = (float*)d_out;

    // ws layout: [0,128) counts (32 ints, padded)
    //            [128, 128 + 1 MB) sums (NCH * ND floats)
    //            [128 + 1 MB, +512 KB) lists (NCH * NB ints)
    int*   counts = (int*)d_ws;
    float* sums   = (float*)((char*)d_ws + 128);
    int*   lists  = (int*)((char*)d_ws + 128 + (size_t)NCH * ND * sizeof(float));

    hipMemsetAsync(d_ws, 0, 128 + (size_t)NCH * ND * sizeof(float), stream);
    build_lists_kernel<<<(NB + 255) / 256, 256, 0, stream>>>(ch, counts, lists);

    const int grid = NCH * NCHUNK * NSPLIT;  // 2048 blocks
    copy_reduce_kernel<<<grid, 256, 0, stream>>>(z, counts, lists, out, sums);
    broadcast_kernel<<<grid, 256, 0, stream>>>(counts, lists, sums, out);
}